// Round 10
// baseline (30.138 us; speedup 1.0000x reference)
//
#include <hip/hip_runtime.h>
#include <hip/hip_fp16.h>

#define DIM 192
#define RMAX 26   // per-16-row tile staged span <= 25 for ds>=48 (sr<4)

typedef float v2f __attribute__((ext_vector_type(2)));

// nearest-resample index map for pass 1 (mid index t -> vol index),
// bit-exact with: clip(round(clip(t / dz, 0, 192)), 0, 191)
__device__ __forceinline__ int nearest_map(int t, float dz) {
    float dl = (float)t / dz;                 // same float div as jnp
    dl = fminf(fmaxf(dl, 0.0f), 192.0f);      // layer clip to [0, inshape]
    float r = rintf(dl);                      // round half-to-even == jnp.round
    r = fminf(r, 191.0f);                     // interp_nearest clip
    return (int)r;
}

// full per-axis LUT entry, identical float-op order to the reference:
// l = i / (192/dsf), clip, floor/ceil-clip, w0 = f1 - l; nearest on corners.
__device__ __forceinline__ void lut_entry(int i, float uz, float dz,
                                          float& w0, int& n0, int& n1) {
    float l = (float)i / uz;
    l = fminf(fmaxf(l, 0.0f), 191.0f);
    const float f0 = floorf(l);
    const float f1 = fminf(f0 + 1.0f, 191.0f);
    w0 = f1 - l;
    n0 = nearest_map((int)f0, dz);
    n1 = nearest_map((int)f1, dz);
}

__device__ __forceinline__ unsigned int pack_h2(float a, float b) {
    __half2 h = __floats2half2_rn(a, b);
    return *reinterpret_cast<unsigned int*>(&h);
}

__device__ __forceinline__ v2f unpack_h2(unsigned int u) {
    __half2 h = *reinterpret_cast<__half2*>(&u);
    float2 f = __half22float2(h);
    v2f r; r.x = f.x; r.y = f.y;
    return r;
}

// ---- single fused kernel: in-block LUT + fp16-pair LDS staging + lerp ----
// Block: one (b,x), ONE 16-row y-tile, 256 threads (4 waves).
// LDS 20160 B -> 8 blocks/CU = 32 waves/CU.
__global__ __launch_bounds__(256, 8) void mimic_acq_one_kernel(
    const float* __restrict__ vol,    // [2,192,192,192,1]
    const float* __restrict__ sres,   // [2,3]
    float* __restrict__ out)          // [2,192,192,192,1]
{
    __shared__ unsigned int lds[RMAX * DIM];   // 19968 B
    __shared__ float yw[16];
    __shared__ int   yn0[16], yn1[16];

    const int tz  = threadIdx.x;            // 0..63  (z lane)
    const int ty  = threadIdx.y;            // 0..3
    const int tid = ty * 64 + tz;

    const int bid = blockIdx.x;             // 0..4607
    const int wg  = (bid & 7) * 576 + (bid >> 3);   // XCD-chunked (4608 = 8*576)
    const int bx  = wg / 12;                // b*192 + x
    const int tile = wg % 12;               // ytile
    const int b   = (bx >= DIM) ? 1 : 0;
    const int x   = bx - b * DIM;
    const int y0t = tile * 16;

    // per-axis constants (exact op order: ds = int(192/sr); uz = 192/dsf; dz = dsf/192)
    const float srx = sres[b * 3 + 0];
    const float sry = sres[b * 3 + 1];
    const float srz = sres[b * 3 + 2];
    const float dsxf = (float)(int)(192.0f / srx);
    const float dsyf = (float)(int)(192.0f / sry);
    const float dszf = (float)(int)(192.0f / srz);
    const float uzx = 192.0f / dsxf, dzx = dsxf / 192.0f;
    const float uzy = 192.0f / dsyf, dzy = dsyf / 192.0f;
    const float uzz = 192.0f / dszf, dzz = dszf / 192.0f;

    // x entry (all threads, block-uniform)
    float w0x; int nx0, nx1;
    lut_entry(x, uzx, dzx, w0x, nx0, nx1);
    const float w1x = 1.0f - w0x;

    // y staging range: nymin = n0(y0t), nymax = n1(y0t+15)  (monotone in y)
    float wt_; int nymin, nt_, nb_, nymax;
    lut_entry(y0t,      uzy, dzy, wt_, nymin, nt_);
    lut_entry(y0t + 15, uzy, dzy, wt_, nb_,   nymax);
    const int R = nymax - nymin + 1;        // <= 25 for sr in [1,4)

    // y entries for this tile -> small LDS side arrays
    if (tid < 16) {
        float w0; int n0, n1;
        lut_entry(y0t + tid, uzy, dzy, w0, n0, n1);
        yw[tid]  = w0;
        yn0[tid] = n0;
        yn1[tid] = n1;
    }

    // ---- stage (load f32 pairs, pack to half2) ----
    {
        const float* vb = vol + (size_t)b * (DIM * DIM * DIM);
        const float* r0 = vb + ((size_t)nx0 * DIM + nymin) * DIM;
        const float* r1 = vb + ((size_t)nx1 * DIM + nymin) * DIM;
        const int C = R * 48;
        for (int c = tid; c < C; c += 256) {
            const int yy = c / 48;
            const int z4 = (c - yy * 48) * 4;
            const float4 v0 = *(const float4*)(r0 + yy * DIM + z4);
            const float4 v1 = *(const float4*)(r1 + yy * DIM + z4);
            uint4 q;
            q.x = pack_h2(v0.x, v1.x);
            q.y = pack_h2(v0.y, v1.y);
            q.z = pack_h2(v0.z, v1.z);
            q.w = pack_h2(v0.w, v1.w);
            *(uint4*)&lds[yy * DIM + z4] = q;
        }
    }

    // z entries for this lane's 3 z positions (division latency overlaps staging)
    float w0zk[3];
    int   zz0[3], zz1[3];
#pragma unroll
    for (int k = 0; k < 3; ++k) {
        lut_entry(tz + k * 64, uzz, dzz, w0zk[k], zz0[k], zz1[k]);
    }

    __syncthreads();

    // ---- compute: 4 y rows x 3 z per thread ----
#pragma unroll
    for (int yj = 0; yj < 4; ++yj) {
        const int ly = ty * 4 + yj;
        const int y  = y0t + ly;
        const float w0y = yw[ly], w1y = 1.0f - w0y;
        const int rr0 = (yn0[ly] - nymin) * DIM;
        const int rr1 = (yn1[ly] - nymin) * DIM;
        float* ob = out + ((size_t)bx * DIM + y) * DIM + tz;
#pragma unroll
        for (int k = 0; k < 3; ++k) {
            const v2f p00 = unpack_h2(lds[rr0 + zz0[k]]);   // {v000, v100}
            const v2f p01 = unpack_h2(lds[rr1 + zz0[k]]);   // {v010, v110}
            const v2f p10 = unpack_h2(lds[rr0 + zz1[k]]);   // {v001, v101}
            const v2f p11 = unpack_h2(lds[rr1 + zz1[k]]);   // {v011, v111}
            const float wz0 = w0zk[k];
            const float wz1 = 1.0f - wz0;
            const v2f l0 = p00 * wz0 + p10 * wz1;   // z-lerp at y0
            const v2f l1 = p01 * wz0 + p11 * wz1;   // z-lerp at y1
            const v2f m  = l0 * w0y + l1 * w1y;     // y-lerp
            const float r = m.x * w0x + m.y * w1x;  // x-lerp
            __builtin_nontemporal_store(r, ob + k * 64);
        }
    }
}

extern "C" void kernel_launch(void* const* d_in, const int* in_sizes, int n_in,
                              void* d_out, int out_size, void* d_ws, size_t ws_size,
                              hipStream_t stream) {
    const float* vol  = (const float*)d_in[0];
    const float* sres = (const float*)d_in[1];
    float* out = (float*)d_out;

    dim3 block(64, 4, 1);
    dim3 grid(4608, 1, 1);   // (b*192+x) * 12 ytiles, XCD-swizzled in-kernel
    hipLaunchKernelGGL(mimic_acq_one_kernel, grid, block, 0, stream, vol, sres, out);
}

// Round 11
// 27.640 us; speedup vs baseline: 1.0904x; 1.0904x over previous
//
#include <hip/hip_runtime.h>
#include <hip/hip_fp16.h>

#define DIM 192
#define RMAX 26   // per-16-row tile staged span <= 25 for ds>=48 (sr<4)

typedef _Float16 h2v __attribute__((ext_vector_type(2)));
typedef float v2f __attribute__((ext_vector_type(2)));

// nearest-resample index map for pass 1 (mid index t -> vol index),
// bit-exact with: clip(round(clip(t / dz, 0, 192)), 0, 191)
__device__ __forceinline__ int nearest_map(int t, float dz) {
    float dl = (float)t / dz;                 // same float div as jnp
    dl = fminf(fmaxf(dl, 0.0f), 192.0f);      // layer clip to [0, inshape]
    float r = rintf(dl);                      // round half-to-even == jnp.round
    r = fminf(r, 191.0f);                     // interp_nearest clip
    return (int)r;
}

// ---- Kernel 1: per-(batch,axis,i) LUT: {w0, n0, n1} (raw indices) ----
__global__ __launch_bounds__(192) void build_lut_kernel(
    const float* __restrict__ sres,   // [2,3]
    float4* __restrict__ lut)         // [2*3*192]
{
    const int e = blockIdx.x * 192 + threadIdx.x;   // e in [0, 1152)
    if (e >= 2 * 3 * DIM) return;
    const int i  = e % DIM;
    const int ba = e / DIM;            // b*3 + axis

    const float sr = sres[ba];
    const int   ds = (int)(192.0f / sr);     // int32 truncation, as astype
    const float dsf = (float)ds;

    // pass-2 trilinear coordinate (exact op order of reference)
    const float uz = 192.0f / dsf;
    float l = (float)i / uz;
    l = fminf(fmaxf(l, 0.0f), 191.0f);
    const float f0 = floorf(l);
    const float f1 = fminf(f0 + 1.0f, 191.0f);
    const float w0 = f1 - l;

    // pass-1 nearest map applied to both corners
    const float dz = dsf / 192.0f;
    const int n0 = nearest_map((int)f0, dz);
    const int n1 = nearest_map((int)f1, dz);

    float4 v;
    v.x = w0;
    v.y = __int_as_float(n0);
    v.z = __int_as_float(n1);
    v.w = 0.0f;
    lut[e] = v;
}

__device__ __forceinline__ unsigned int pack_h2(float a, float b) {
    __half2 h = __floats2half2_rn(a, b);
    return *reinterpret_cast<unsigned int*>(&h);
}

__device__ __forceinline__ h2v as_h2v(unsigned int u) {
    union { unsigned int u; h2v h; } cv;
    cv.u = u;
    return cv.h;
}

__device__ __forceinline__ h2v splat_h(float f) {
    const _Float16 h = (_Float16)f;
    h2v r; r.x = h; r.y = h;
    return r;
}

// ---- Kernel 2: small-block LDS resample, fp16-pair LDS + fp16 pk lerp ----
// Block: one (b,x), ONE 16-row y-tile, 256 threads (4 waves).
// 19.97 KB LDS + <=64 VGPR -> 8 independent blocks/CU = 32 waves/CU.
__global__ __launch_bounds__(256, 8) void mimic_acq_sm_kernel(
    const float* __restrict__ vol,    // [2,192,192,192,1]
    const float4* __restrict__ lut,   // [2*3*192]
    float* __restrict__ out)          // [2,192,192,192,1]
{
    __shared__ unsigned int lds[RMAX * DIM];   // 19968 B

    const int tz  = threadIdx.x;            // 0..63  (z lane)
    const int ty  = threadIdx.y;            // 0..3
    const int tid = ty * 64 + tz;

    const int bid = blockIdx.x;             // 0..4607
    const int wg  = (bid & 7) * 576 + (bid >> 3);   // XCD-chunked (4608 = 8*576)
    const int bx  = wg / 12;                // b*192 + x
    const int tile = wg % 12;               // ytile
    const int b   = (bx >= DIM) ? 1 : 0;
    const int x   = bx - b * DIM;
    const int y0t = tile * 16;

    // x corners (block-uniform)
    const float4 ex = lut[(b * 3 + 0) * DIM + x];
    const float w0x = ex.x, w1x = 1.0f - ex.x;
    const int nx0 = __float_as_int(ex.y), nx1 = __float_as_int(ex.z);

    const float* vb = vol + (size_t)b * (DIM * DIM * DIM);

    // y staging range (n0/n1 monotone in y)
    const float4 eyf = lut[(b * 3 + 1) * DIM + y0t];
    const float4 eyl = lut[(b * 3 + 1) * DIM + y0t + 15];
    const int nymin = __float_as_int(eyf.y);
    const int R = __float_as_int(eyl.z) - nymin + 1;   // <= 25

    // ---- stage (load f32 pairs, pack to half2) ----
    {
        const float* r0 = vb + ((size_t)nx0 * DIM + nymin) * DIM;
        const float* r1 = vb + ((size_t)nx1 * DIM + nymin) * DIM;
        const int C = R * 48;
        for (int c = tid; c < C; c += 256) {
            const int yy = c / 48;
            const int z4 = (c - yy * 48) * 4;
            const float4 v0 = *(const float4*)(r0 + yy * DIM + z4);
            const float4 v1 = *(const float4*)(r1 + yy * DIM + z4);
            uint4 q;
            q.x = pack_h2(v0.x, v1.x);
            q.y = pack_h2(v0.y, v1.y);
            q.z = pack_h2(v0.z, v1.z);
            q.w = pack_h2(v0.w, v1.w);
            *(uint4*)&lds[yy * DIM + z4] = q;
        }
    }

    // z entries for this lane's 3 z positions (latency overlaps staging)
    h2v wz0h[3], wz1h[3];
    int zz0[3], zz1[3];
#pragma unroll
    for (int k = 0; k < 3; ++k) {
        const float4 ez = lut[(b * 3 + 2) * DIM + tz + k * 64];
        wz0h[k] = splat_h(ez.x);
        wz1h[k] = splat_h(1.0f - ez.x);
        zz0[k]  = __float_as_int(ez.y);
        zz1[k]  = __float_as_int(ez.z);
    }

    __syncthreads();

    // ---- compute: 4 y rows x 3 z per thread, fp16 packed lerp ----
#pragma unroll
    for (int yj = 0; yj < 4; ++yj) {
        const int y = y0t + ty * 4 + yj;
        const float4 ey = lut[(b * 3 + 1) * DIM + y];
        const h2v w0yh = splat_h(ey.x);
        const h2v w1yh = splat_h(1.0f - ey.x);
        const int rr0 = (__float_as_int(ey.y) - nymin) * DIM;
        const int rr1 = (__float_as_int(ey.z) - nymin) * DIM;
        float* ob = out + ((size_t)bx * DIM + y) * DIM + tz;
#pragma unroll
        for (int k = 0; k < 3; ++k) {
            const h2v p00 = as_h2v(lds[rr0 + zz0[k]]);   // {v000, v100}
            const h2v p01 = as_h2v(lds[rr1 + zz0[k]]);   // {v010, v110}
            const h2v p10 = as_h2v(lds[rr0 + zz1[k]]);   // {v001, v101}
            const h2v p11 = as_h2v(lds[rr1 + zz1[k]]);   // {v011, v111}

            const h2v l0 = p00 * wz0h[k] + p10 * wz1h[k];   // z-lerp at y0 (pk f16)
            const h2v l1 = p01 * wz0h[k] + p11 * wz1h[k];   // z-lerp at y1
            const h2v m  = l0 * w0yh + l1 * w1yh;           // y-lerp (pk f16)

            const float r = (float)m.x * w0x + (float)m.y * w1x;  // x-lerp f32
            __builtin_nontemporal_store(r, ob + k * 64);
        }
    }
}

// Fallback (round-1 kernel) in case ws is too small for the LUT.
__global__ __launch_bounds__(256) void mimic_acq_fused_kernel(
    const float* __restrict__ vol,
    const float* __restrict__ sres,
    float* __restrict__ out)
{
    const int z  = blockIdx.x * 64 + threadIdx.x;
    const int y  = blockIdx.y * 4  + threadIdx.y;
    const int bx = blockIdx.z;
    const int b  = (bx >= DIM) ? 1 : 0;
    const int x  = bx - b * DIM;

    const float srx = sres[b * 3 + 0];
    const float sry = sres[b * 3 + 1];
    const float srz = sres[b * 3 + 2];
    const int dsx = (int)(192.0f / srx);
    const int dsy = (int)(192.0f / sry);
    const int dsz = (int)(192.0f / srz);
    const float dsxf = (float)dsx, dsyf = (float)dsy, dszf = (float)dsz;

    const float uzx = 192.0f / dsxf;
    const float uzy = 192.0f / dsyf;
    const float uzz = 192.0f / dszf;

    float lx = (float)x / uzx; lx = fminf(fmaxf(lx, 0.0f), 191.0f);
    float ly = (float)y / uzy; ly = fminf(fmaxf(ly, 0.0f), 191.0f);
    float lz = (float)z / uzz; lz = fminf(fmaxf(lz, 0.0f), 191.0f);

    const float f0x = floorf(lx), f0y = floorf(ly), f0z = floorf(lz);
    const float f1x = fminf(f0x + 1.0f, 191.0f);
    const float f1y = fminf(f0y + 1.0f, 191.0f);
    const float f1z = fminf(f0z + 1.0f, 191.0f);

    const float w0x = f1x - lx, w1x = 1.0f - w0x;
    const float w0y = f1y - ly, w1y = 1.0f - w0y;
    const float w0z = f1z - lz, w1z = 1.0f - w0z;

    const float dzx = dsxf / 192.0f;
    const float dzy = dsyf / 192.0f;
    const float dzz = dszf / 192.0f;

    const int nx0 = nearest_map((int)f0x, dzx), nx1 = nearest_map((int)f1x, dzx);
    const int ny0 = nearest_map((int)f0y, dzy), ny1 = nearest_map((int)f1y, dzy);
    const int nz0 = nearest_map((int)f0z, dzz), nz1 = nearest_map((int)f1z, dzz);

    const float* vb = vol + (size_t)b * (DIM * DIM * DIM);

    float acc = 0.0f;
#pragma unroll
    for (int c = 0; c < 8; ++c) {
        const int xi = (c & 1) ? nx1 : nx0;
        const int yi = (c & 2) ? ny1 : ny0;
        const int zi = (c & 4) ? nz1 : nz0;
        const float w = ((c & 1) ? w1x : w0x)
                      * ((c & 2) ? w1y : w0y)
                      * ((c & 4) ? w1z : w0z);
        acc += w * vb[((size_t)xi * DIM + yi) * DIM + zi];
    }

    out[((size_t)bx * DIM + y) * DIM + z] = acc;
}

extern "C" void kernel_launch(void* const* d_in, const int* in_sizes, int n_in,
                              void* d_out, int out_size, void* d_ws, size_t ws_size,
                              hipStream_t stream) {
    const float* vol  = (const float*)d_in[0];
    const float* sres = (const float*)d_in[1];
    float* out = (float*)d_out;

    const size_t lut_bytes = (size_t)(2 * 3 * DIM) * sizeof(float4);

    if (ws_size >= lut_bytes) {
        float4* lut = (float4*)d_ws;
        hipLaunchKernelGGL(build_lut_kernel, dim3(6), dim3(192), 0, stream, sres, lut);
        dim3 block(64, 4, 1);
        dim3 grid(4608, 1, 1);   // (b*192+x) * 12 ytiles, XCD-swizzled in-kernel
        hipLaunchKernelGGL(mimic_acq_sm_kernel, grid, block, 0, stream, vol, lut, out);
    } else {
        dim3 block(64, 4, 1);
        dim3 grid(DIM / 64, DIM / 4, 2 * DIM);
        hipLaunchKernelGGL(mimic_acq_fused_kernel, grid, block, 0, stream, vol, sres, out);
    }
}

// Round 12
// 23.811 us; speedup vs baseline: 1.2657x; 1.1608x over previous
//
#include <hip/hip_runtime.h>
#include <hip/hip_fp16.h>

#define DIM 192
#define RROWS 25  // provable: staged span <= 15 + 2*(192/ds) + 1 <= 24 for ds>=48 (sr in [1,4))

typedef _Float16 h2v __attribute__((ext_vector_type(2)));

// nearest-resample index map for pass 1 (mid index t -> vol index),
// bit-exact with: clip(round(clip(t / dz, 0, 192)), 0, 191)
__device__ __forceinline__ int nearest_map(int t, float dz) {
    float dl = (float)t / dz;                 // same float div as jnp
    dl = fminf(fmaxf(dl, 0.0f), 192.0f);      // layer clip to [0, inshape]
    float r = rintf(dl);                      // round half-to-even == jnp.round
    r = fminf(r, 191.0f);                     // interp_nearest clip
    return (int)r;
}

// packed per-axis LUT entry: half_bits(w0) | n0<<16 | n1<<24  (n <= 191 < 256)
// identical float-op order to the reference pipeline.
__device__ __forceinline__ unsigned int make_entry(int i, float sr) {
    const float dsf = (float)(int)(192.0f / sr);   // ds = int32(192/sr)
    const float uz  = 192.0f / dsf;
    const float dz  = dsf / 192.0f;
    float l = (float)i / uz;
    l = fminf(fmaxf(l, 0.0f), 191.0f);
    const float f0 = floorf(l);
    const float f1 = fminf(f0 + 1.0f, 191.0f);
    const float w0 = f1 - l;
    const int n0 = nearest_map((int)f0, dz);
    const int n1 = nearest_map((int)f1, dz);
    const __half hw = __float2half(w0);
    return (unsigned int)__half_as_ushort(hw) | ((unsigned int)n0 << 16) | ((unsigned int)n1 << 24);
}

__device__ __forceinline__ unsigned int pack_h2(float a, float b) {
    __half2 h = __floats2half2_rn(a, b);
    return *reinterpret_cast<unsigned int*>(&h);
}

__device__ __forceinline__ h2v as_h2v(unsigned int u) {
    union { unsigned int u; h2v h; } cv;
    cv.u = u;
    return cv.h;
}

// broadcast the low half of u into both lanes of an h2v
__device__ __forceinline__ h2v bcast_h(unsigned int u) {
    union { unsigned int u; h2v h; } cv;
    cv.u = (u & 0xffffu) * 0x10001u;
    return cv.h;
}

// ---- single fused kernel ----
// Block: one (b,x), ONE 16-row y-tile, 256 threads (4 waves).
// Distributed LUT build: 1 entry chain per thread (192 z + 16 y + 1 x = 209),
// shared via LDS. fp16-pair main tile + fp16 packed lerp. 20040 B LDS ->
// 8 blocks/CU = 32 waves/CU. XCD-chunked block swizzle.
__global__ __launch_bounds__(256, 8) void mimic_acq_f1_kernel(
    const float* __restrict__ vol,    // [2,192,192,192,1]
    const float* __restrict__ sres,   // [2,3]
    float* __restrict__ out)          // [2,192,192,192,1]
{
    __shared__ unsigned int lds[RROWS * DIM];   // 19200 B
    __shared__ unsigned int zside[DIM];         // 768 B
    __shared__ unsigned int yside[16];          // 64 B
    __shared__ float xw_s;                      // 4 B
    __shared__ unsigned int xn_s;               // 4 B

    const int tz  = threadIdx.x;            // 0..63  (z lane)
    const int ty  = threadIdx.y;            // 0..3
    const int tid = ty * 64 + tz;

    const int bid = blockIdx.x;             // 0..4607
    const int wg  = (bid & 7) * 576 + (bid >> 3);   // XCD-chunked (4608 = 8*576)
    const int bx  = wg / 12;                // b*192 + x
    const int tile = wg % 12;               // ytile
    const int b   = (bx >= DIM) ? 1 : 0;
    const int x   = bx - b * DIM;
    const int y0t = tile * 16;

    // ---- distributed LUT-entry build: one chain per thread ----
    if (tid < DIM) {
        zside[tid] = make_entry(tid, sres[b * 3 + 2]);
    } else if (tid < DIM + 16) {
        yside[tid - DIM] = make_entry(y0t + (tid - DIM), sres[b * 3 + 1]);
    } else if (tid == DIM + 16) {
        // x entry with f32 weight (final lerp stays f32)
        const float srx = sres[b * 3 + 0];
        const float dsf = (float)(int)(192.0f / srx);
        const float uz  = 192.0f / dsf;
        const float dz  = dsf / 192.0f;
        float l = (float)x / uz;
        l = fminf(fmaxf(l, 0.0f), 191.0f);
        const float f0 = floorf(l);
        const float f1 = fminf(f0 + 1.0f, 191.0f);
        xw_s = f1 - l;
        xn_s = (unsigned int)nearest_map((int)f0, dz)
             | ((unsigned int)nearest_map((int)f1, dz) << 8);
    }
    __syncthreads();

    // block-uniform x / y-range from LDS
    const float w0x = xw_s, w1x = 1.0f - xw_s;
    const unsigned int xpk = xn_s;
    const int nx0 = (int)(xpk & 0xffu);
    const int nx1 = (int)(xpk >> 8);
    const int nymin = (int)((yside[0] >> 16) & 0xffu);
    const int R = (int)(yside[15] >> 24) - nymin + 1;   // <= 25

    // ---- stage (load f32 pairs, pack to half2) ----
    {
        const float* vb = vol + (size_t)b * (DIM * DIM * DIM);
        const float* r0 = vb + ((size_t)nx0 * DIM + nymin) * DIM;
        const float* r1 = vb + ((size_t)nx1 * DIM + nymin) * DIM;
        const int C = R * 48;
        for (int c = tid; c < C; c += 256) {
            const int yy = c / 48;
            const int z4 = (c - yy * 48) * 4;
            const float4 v0 = *(const float4*)(r0 + yy * DIM + z4);
            const float4 v1 = *(const float4*)(r1 + yy * DIM + z4);
            uint4 q;
            q.x = pack_h2(v0.x, v1.x);
            q.y = pack_h2(v0.y, v1.y);
            q.z = pack_h2(v0.z, v1.z);
            q.w = pack_h2(v0.w, v1.w);
            *(uint4*)&lds[yy * DIM + z4] = q;
        }
    }

    // z entries for this lane's 3 z positions (LDS reads overlap staging)
    h2v wz0h[3], wz1h[3];
    int zz0[3], zz1[3];
    const h2v ones = { (_Float16)1.0f, (_Float16)1.0f };
#pragma unroll
    for (int k = 0; k < 3; ++k) {
        const unsigned int u = zside[tz + k * 64];
        wz0h[k] = bcast_h(u);
        wz1h[k] = ones - wz0h[k];
        zz0[k]  = (int)((u >> 16) & 0xffu);
        zz1[k]  = (int)(u >> 24);
    }

    __syncthreads();

    // ---- compute: 4 y rows x 3 z per thread, fp16 packed lerp ----
#pragma unroll
    for (int yj = 0; yj < 4; ++yj) {
        const int ly = ty * 4 + yj;
        const int y  = y0t + ly;
        const unsigned int uy = yside[ly];
        const h2v w0yh = bcast_h(uy);
        const h2v w1yh = ones - w0yh;
        const int rr0 = ((int)((uy >> 16) & 0xffu) - nymin) * DIM;
        const int rr1 = ((int)(uy >> 24) - nymin) * DIM;
        float* ob = out + ((size_t)bx * DIM + y) * DIM + tz;
#pragma unroll
        for (int k = 0; k < 3; ++k) {
            const h2v p00 = as_h2v(lds[rr0 + zz0[k]]);   // {v000, v100}
            const h2v p01 = as_h2v(lds[rr1 + zz0[k]]);   // {v010, v110}
            const h2v p10 = as_h2v(lds[rr0 + zz1[k]]);   // {v001, v101}
            const h2v p11 = as_h2v(lds[rr1 + zz1[k]]);   // {v011, v111}

            const h2v l0 = p00 * wz0h[k] + p10 * wz1h[k];   // z-lerp at y0 (pk f16)
            const h2v l1 = p01 * wz0h[k] + p11 * wz1h[k];   // z-lerp at y1
            const h2v m  = l0 * w0yh + l1 * w1yh;           // y-lerp (pk f16)

            const float r = (float)m.x * w0x + (float)m.y * w1x;  // x-lerp f32
            __builtin_nontemporal_store(r, ob + k * 64);
        }
    }
}

extern "C" void kernel_launch(void* const* d_in, const int* in_sizes, int n_in,
                              void* d_out, int out_size, void* d_ws, size_t ws_size,
                              hipStream_t stream) {
    const float* vol  = (const float*)d_in[0];
    const float* sres = (const float*)d_in[1];
    float* out = (float*)d_out;

    dim3 block(64, 4, 1);
    dim3 grid(4608, 1, 1);   // (b*192+x) * 12 ytiles, XCD-swizzled in-kernel
    hipLaunchKernelGGL(mimic_acq_f1_kernel, grid, block, 0, stream, vol, sres, out);
}